// Round 8
// baseline (49.329 us; speedup 1.0000x reference)
//
#include <hip/hip_runtime.h>

// Problem constants (match reference setup_inputs)
#define B_ 8
#define T_ 1024
#define S_ 4096
#define H_ 256

#define STRIP 64           // tokens per K1 wave
#define UNROLL 64          // tag rows loaded per early-exit check

// K1: per-wave top-down early-exit column-max. One wave per (b, 64-token
// strip); lane owns one token column. 64 independent 256B row-loads in
// flight (16KB/wave) hide HBM latency even at 2 waves/CU. Exit: once every
// lane has seen a covering tag, lower rows can't raise the max -> break.
// Ascending-overwrite within the chunk gives the in-chunk max; chunks are
// visited top-down so max() across chunks is correct. Zero __syncthreads.
// Expensive strips (low s0) dispatched first -> dynamic backfill approximates
// LPT, so data-adaptive savings translate into makespan.
__global__ void __launch_bounds__(64) colmax_wave_kernel(const float* __restrict__ ttt,
                                                         int* __restrict__ L) {
    const int strippos = blockIdx.x >> 3;       // 0..63, low s0 (expensive) first
    const int b  = blockIdx.x & 7;
    const int s0 = strippos * STRIP;
    const int lane = threadIdx.x;
    const float* col = ttt + (size_t)b * T_ * S_ + s0 + lane;

    int found = -1;
    for (int thi = T_; thi > 0; thi -= UNROLL) {
        const int t0 = thi - UNROLL;
        const float* p = col + (size_t)t0 * S_;
        float v[UNROLL];
#pragma unroll
        for (int j = 0; j < UNROLL; ++j)
            v[j] = p[(size_t)j * S_];
        int lm = -1;
#pragma unroll
        for (int j = 0; j < UNROLL; ++j)
            if (v[j] > 0.0f) lm = t0 + j;       // ascending j -> chunk max
        found = max(found, lm);
        if (__all(found >= 0)) break;
    }
    L[b * S_ + s0 + lane] = found;
}

// K2: gather + mean + seq_emb, 4 tags per wave. Each wave scans L[b,:] once
// (int4/lane, 16 iters) and ballots against 4 consecutive targets -> 4x less
// L traffic than 1 tag/wave. Matching tokens contribute coalesced
// float4-per-lane rows of inputs. No atomics. 2048 waves (8/CU).
__global__ void __launch_bounds__(256) gather4_kernel(const float* __restrict__ inputs,
                                                      const int* __restrict__ L,
                                                      const float* __restrict__ seq_emb,
                                                      float* __restrict__ out) {
    const int wid  = threadIdx.x >> 6;
    const int lane = threadIdx.x & 63;
    const int gw   = blockIdx.x * 4 + wid;      // 0..2047
    const int bt0  = gw * 4;                    // 4 consecutive (b,t) rows
    const int b    = bt0 >> 10;
    const int tb   = bt0 & (T_ - 1);

    const int4* Lb4 = reinterpret_cast<const int4*>(L + b * S_);
    const float4* in4 = reinterpret_cast<const float4*>(inputs);

    float4 acc[4];
    int cnt[4];
#pragma unroll
    for (int k = 0; k < 4; ++k) { acc[k] = {0.f, 0.f, 0.f, 0.f}; cnt[k] = 0; }

    for (int q = 0; q < S_ / 4; q += 64) {      // int4 index space, 16 iters
        int4 v = Lb4[q + lane];
#pragma unroll
        for (int k = 0; k < 4; ++k) {           // static after unroll (rule #20)
            const int t = tb + k;
            unsigned long long m;
            m = __ballot(v.x == t);
            while (m) { int l = __ffsll(m) - 1; m &= m - 1;
                float4 r = in4[(size_t)(b * S_ + (q + l) * 4 + 0) * (H_ / 4) + lane];
                acc[k].x += r.x; acc[k].y += r.y; acc[k].z += r.z; acc[k].w += r.w; cnt[k]++; }
            m = __ballot(v.y == t);
            while (m) { int l = __ffsll(m) - 1; m &= m - 1;
                float4 r = in4[(size_t)(b * S_ + (q + l) * 4 + 1) * (H_ / 4) + lane];
                acc[k].x += r.x; acc[k].y += r.y; acc[k].z += r.z; acc[k].w += r.w; cnt[k]++; }
            m = __ballot(v.z == t);
            while (m) { int l = __ffsll(m) - 1; m &= m - 1;
                float4 r = in4[(size_t)(b * S_ + (q + l) * 4 + 2) * (H_ / 4) + lane];
                acc[k].x += r.x; acc[k].y += r.y; acc[k].z += r.z; acc[k].w += r.w; cnt[k]++; }
            m = __ballot(v.w == t);
            while (m) { int l = __ffsll(m) - 1; m &= m - 1;
                float4 r = in4[(size_t)(b * S_ + (q + l) * 4 + 3) * (H_ / 4) + lane];
                acc[k].x += r.x; acc[k].y += r.y; acc[k].z += r.z; acc[k].w += r.w; cnt[k]++; }
        }
    }

#pragma unroll
    for (int k = 0; k < 4; ++k) {
        float inv = (cnt[k] > 0) ? (1.0f / (float)cnt[k]) : 0.0f;  // empty -> emb
        float4 e = reinterpret_cast<const float4*>(seq_emb)[(tb + k) * (H_ / 4) + lane];
        float4 o;
        o.x = acc[k].x * inv + e.x;
        o.y = acc[k].y * inv + e.y;
        o.z = acc[k].z * inv + e.z;
        o.w = acc[k].w * inv + e.w;
        reinterpret_cast<float4*>(out)[(size_t)(bt0 + k) * (H_ / 4) + lane] = o;
    }
}

extern "C" void kernel_launch(void* const* d_in, const int* in_sizes, int n_in,
                              void* d_out, int out_size, void* d_ws, size_t ws_size,
                              hipStream_t stream) {
    const float* inputs  = (const float*)d_in[0];   // [B,S,H]
    const float* ttt     = (const float*)d_in[1];   // [B,T,S]
    const float* seq_emb = (const float*)d_in[2];   // [T,H]
    float* out = (float*)d_out;                     // [B,T,H]
    int* L = (int*)d_ws;                            // B*S ints (128 KiB)

    // K1: per-wave early-exit column-max (512 one-wave blocks, expensive first)
    colmax_wave_kernel<<<B_ * (S_ / STRIP), 64, 0, stream>>>(ttt, L);

    // K2: fused gather + mean + emb, 4 tags/wave (512 blocks x 4 waves)
    gather4_kernel<<<B_ * T_ / 16, 256, 0, stream>>>(inputs, L, seq_emb, out);
}

// Round 9
// 33.207 us; speedup vs baseline: 1.4855x; 1.4855x over previous
//
#include <hip/hip_runtime.h>

// Problem constants (match reference setup_inputs)
#define B_ 8
#define T_ 1024
#define S_ 4096
#define H_ 256

#define STRIP 64           // tokens per K1 block
#define CHUNK 128          // tag rows per early-exit check

// K1: deterministic column-max with top-down early exit + LPT block ordering.
// (Unchanged from R7 — proven 30.5us total, absmax 0.0.)
__global__ void __launch_bounds__(256) colmax_lpt_kernel(const float* __restrict__ ttt,
                                                         int* __restrict__ L) {
    __shared__ int red[4][STRIP];
    __shared__ int best[STRIP];
    __shared__ int nf;
    const int strippos = blockIdx.x >> 3;   // 0..63, low s0 (expensive) first
    const int b  = blockIdx.x & 7;
    const int s0 = strippos * STRIP;
    const int w    = threadIdx.x >> 6;
    const int lane = threadIdx.x & 63;
    const int tid  = threadIdx.x;

    if (tid < STRIP) best[tid] = -1;

    const float* colbase = ttt + (size_t)b * T_ * S_ + s0 + lane;

    for (int thi = T_; thi > 0; thi -= CHUNK) {
        const int t0 = thi - CHUNK + w * 32;            // wave's 32 rows
        const float* p = colbase + (size_t)t0 * S_;
        int lm = -1;
#pragma unroll
        for (int hh = 0; hh < 2; ++hh) {
            float v[16];
#pragma unroll
            for (int j = 0; j < 16; ++j)
                v[j] = p[(size_t)(hh * 16 + j) * S_];
#pragma unroll
            for (int j = 0; j < 16; ++j)
                if (v[j] > 0.0f) lm = t0 + hh * 16 + j; // ascending -> max
        }
        red[w][lane] = lm;
        __syncthreads();
        if (tid == 0) nf = 0;
        __syncthreads();
        if (tid < STRIP) {
            int m = max(max(red[0][tid], red[1][tid]),
                        max(red[2][tid], red[3][tid]));
            int bb = max(best[tid], m);
            best[tid] = bb;
            if (bb < 0) atomicOr(&nf, 1);
        }
        __syncthreads();
        if (nf == 0) break;                 // all tokens found -> done
    }

    if (tid < STRIP) L[b * S_ + s0 + tid] = best[tid];
}

// K2: gather + mean + seq_emb, TWO tags per wave (single change vs R7).
// Each wave scans L[b,:] once (int4/lane, 16 iters) and ballots against the
// pair (t0, t1=t0+1) -> halves L2 scan traffic (134 -> 67 MB) vs 1 tag/wave.
// Dual-row gather logic validated in R5 phase C (absmax 0.0).
__global__ void __launch_bounds__(256) gather2_kernel(const float* __restrict__ inputs,
                                                      const int* __restrict__ L,
                                                      const float* __restrict__ seq_emb,
                                                      float* __restrict__ out) {
    const int wid  = threadIdx.x >> 6;
    const int lane = threadIdx.x & 63;
    const int gw   = blockIdx.x * 4 + wid;       // 0..4095
    const int bt0  = gw * 2;                     // pair of consecutive rows
    const int b  = bt0 >> 10;
    const int t0 = bt0 & (T_ - 1);
    const int t1 = t0 + 1;

    const int4* Lb4 = reinterpret_cast<const int4*>(L + b * S_);
    const float4* in4 = reinterpret_cast<const float4*>(inputs);

    float4 a0 = {0.f, 0.f, 0.f, 0.f}, a1 = {0.f, 0.f, 0.f, 0.f};
    int c0 = 0, c1 = 0;

#pragma unroll 4
    for (int q = 0; q < S_ / 4; q += 64) {       // int4 index space, 16 iters
        int4 v = Lb4[q + lane];
        unsigned long long m;
        m = __ballot(v.x == t0);
        while (m) { int l = __ffsll(m) - 1; m &= m - 1;
            float4 r = in4[(size_t)(b * S_ + (q + l) * 4 + 0) * (H_ / 4) + lane];
            a0.x += r.x; a0.y += r.y; a0.z += r.z; a0.w += r.w; c0++; }
        m = __ballot(v.y == t0);
        while (m) { int l = __ffsll(m) - 1; m &= m - 1;
            float4 r = in4[(size_t)(b * S_ + (q + l) * 4 + 1) * (H_ / 4) + lane];
            a0.x += r.x; a0.y += r.y; a0.z += r.z; a0.w += r.w; c0++; }
        m = __ballot(v.z == t0);
        while (m) { int l = __ffsll(m) - 1; m &= m - 1;
            float4 r = in4[(size_t)(b * S_ + (q + l) * 4 + 2) * (H_ / 4) + lane];
            a0.x += r.x; a0.y += r.y; a0.z += r.z; a0.w += r.w; c0++; }
        m = __ballot(v.w == t0);
        while (m) { int l = __ffsll(m) - 1; m &= m - 1;
            float4 r = in4[(size_t)(b * S_ + (q + l) * 4 + 3) * (H_ / 4) + lane];
            a0.x += r.x; a0.y += r.y; a0.z += r.z; a0.w += r.w; c0++; }
        m = __ballot(v.x == t1);
        while (m) { int l = __ffsll(m) - 1; m &= m - 1;
            float4 r = in4[(size_t)(b * S_ + (q + l) * 4 + 0) * (H_ / 4) + lane];
            a1.x += r.x; a1.y += r.y; a1.z += r.z; a1.w += r.w; c1++; }
        m = __ballot(v.y == t1);
        while (m) { int l = __ffsll(m) - 1; m &= m - 1;
            float4 r = in4[(size_t)(b * S_ + (q + l) * 4 + 1) * (H_ / 4) + lane];
            a1.x += r.x; a1.y += r.y; a1.z += r.z; a1.w += r.w; c1++; }
        m = __ballot(v.z == t1);
        while (m) { int l = __ffsll(m) - 1; m &= m - 1;
            float4 r = in4[(size_t)(b * S_ + (q + l) * 4 + 2) * (H_ / 4) + lane];
            a1.x += r.x; a1.y += r.y; a1.z += r.z; a1.w += r.w; c1++; }
        m = __ballot(v.w == t1);
        while (m) { int l = __ffsll(m) - 1; m &= m - 1;
            float4 r = in4[(size_t)(b * S_ + (q + l) * 4 + 3) * (H_ / 4) + lane];
            a1.x += r.x; a1.y += r.y; a1.z += r.z; a1.w += r.w; c1++; }
    }

    float i0 = (c0 > 0) ? (1.0f / (float)c0) : 0.0f;   // empty row -> just emb
    float i1 = (c1 > 0) ? (1.0f / (float)c1) : 0.0f;
    float4 e0 = reinterpret_cast<const float4*>(seq_emb)[t0 * (H_ / 4) + lane];
    float4 e1 = reinterpret_cast<const float4*>(seq_emb)[t1 * (H_ / 4) + lane];
    float4 o0, o1;
    o0.x = a0.x * i0 + e0.x; o0.y = a0.y * i0 + e0.y;
    o0.z = a0.z * i0 + e0.z; o0.w = a0.w * i0 + e0.w;
    o1.x = a1.x * i1 + e1.x; o1.y = a1.y * i1 + e1.y;
    o1.z = a1.z * i1 + e1.z; o1.w = a1.w * i1 + e1.w;
    reinterpret_cast<float4*>(out)[(size_t)bt0 * (H_ / 4) + lane] = o0;
    reinterpret_cast<float4*>(out)[(size_t)(bt0 + 1) * (H_ / 4) + lane] = o1;
}

extern "C" void kernel_launch(void* const* d_in, const int* in_sizes, int n_in,
                              void* d_out, int out_size, void* d_ws, size_t ws_size,
                              hipStream_t stream) {
    const float* inputs  = (const float*)d_in[0];   // [B,S,H]
    const float* ttt     = (const float*)d_in[1];   // [B,T,S]
    const float* seq_emb = (const float*)d_in[2];   // [T,H]
    float* out = (float*)d_out;                     // [B,T,H]
    int* L = (int*)d_ws;                            // B*S ints (128 KiB)

    // K1: top-down early-exit column-max (unchanged from R7)
    colmax_lpt_kernel<<<B_ * (S_ / STRIP), 256, 0, stream>>>(ttt, L);

    // K2: fused gather + mean + emb, 2 tags/wave (1024 blocks x 4 waves)
    gather2_kernel<<<B_ * T_ / 8, 256, 0, stream>>>(inputs, L, seq_emb, out);
}

// Round 10
// 31.198 us; speedup vs baseline: 1.5812x; 1.0644x over previous
//
#include <hip/hip_runtime.h>

// Problem constants (match reference setup_inputs)
#define B_ 8
#define T_ 1024
#define S_ 4096
#define H_ 256

#define STRIP 64           // tokens per strip
#define CHUNK 128          // tag rows per early-exit check
#define NSTRIPS (B_ * (S_ / STRIP))   // 512

// K1: top-down early-exit column-max with STATIC COST PAIRING.
// 256 blocks (1/CU), each processes strips blockIdx.x and 511-blockIdx.x.
// Strip sid = p*8+b covers tokens [p*64, p*64+64) of batch b; its adaptive
// cost is ~(T - last_tag_rows(p)) and is monotone in p, so pairing p with
// 63-p makes every block's total ~constant (~51% of a full scan) regardless
// of block->CU placement. Within a strip: wave w owns 32 rows of each
// 128-row chunk (coalesced 256B row loads), LDS max-combine, exit when all
// 64 tokens have found a covering tag (lower rows can't raise the max).
__global__ void __launch_bounds__(256) colmax_paired_kernel(const float* __restrict__ ttt,
                                                            int* __restrict__ L) {
    __shared__ int red[4][STRIP];
    __shared__ int best[STRIP];
    __shared__ int nf;
    const int w    = threadIdx.x >> 6;
    const int lane = threadIdx.x & 63;
    const int tid  = threadIdx.x;

#pragma unroll
    for (int half = 0; half < 2; ++half) {
        const int sid = (half == 0) ? blockIdx.x : (NSTRIPS - 1 - blockIdx.x);
        const int p = sid >> 3;
        const int b = sid & 7;
        const int s0 = p * STRIP;

        __syncthreads();                        // protect LDS reuse across halves
        if (tid < STRIP) best[tid] = -1;

        const float* colbase = ttt + (size_t)b * T_ * S_ + s0 + lane;

        for (int thi = T_; thi > 0; thi -= CHUNK) {
            const int t0 = thi - CHUNK + w * 32;            // wave's 32 rows
            const float* pp = colbase + (size_t)t0 * S_;
            int lm = -1;
#pragma unroll
            for (int hh = 0; hh < 2; ++hh) {
                float v[16];
#pragma unroll
                for (int j = 0; j < 16; ++j)
                    v[j] = pp[(size_t)(hh * 16 + j) * S_];
#pragma unroll
                for (int j = 0; j < 16; ++j)
                    if (v[j] > 0.0f) lm = t0 + hh * 16 + j; // ascending -> max
            }
            red[w][lane] = lm;
            __syncthreads();
            if (tid == 0) nf = 0;
            __syncthreads();
            if (tid < STRIP) {
                int m = max(max(red[0][tid], red[1][tid]),
                            max(red[2][tid], red[3][tid]));
                int bb = max(best[tid], m);
                best[tid] = bb;
                if (bb < 0) atomicOr(&nf, 1);
            }
            __syncthreads();
            if (nf == 0) break;                 // all tokens found -> done
        }

        if (tid < STRIP) L[b * S_ + s0 + tid] = best[tid];
    }
}

// K2: gather + mean + seq_emb, fused — EXACT R7 form (proven best, absmax 0.0).
// One wave per (b,t) output row; scans L[b,:] with int4 loads (256 tokens per
// iteration via 4 ballots); each matching token contributes a coalesced
// float4-per-lane row of inputs. No atomics.
__global__ void gather_mean_kernel(const float* __restrict__ inputs,
                                   const int* __restrict__ L,
                                   const float* __restrict__ seq_emb,
                                   float* __restrict__ out) {
    int wid  = threadIdx.x >> 6;
    int lane = threadIdx.x & 63;
    int bt = blockIdx.x * 4 + wid;               // (b*T + t), 4 waves per block
    int b = bt >> 10;                            // / T_
    int t = bt & (T_ - 1);

    const int4* Lb4 = reinterpret_cast<const int4*>(L + b * S_);
    const float4* in4 = reinterpret_cast<const float4*>(inputs);

    float4 acc = {0.0f, 0.0f, 0.0f, 0.0f};
    int c = 0;

#pragma unroll 4
    for (int c0 = 0; c0 < S_ / 4; c0 += 64) {    // int4 index space
        int4 v = Lb4[c0 + lane];
        unsigned long long m0 = __ballot(v.x == t);
        unsigned long long m1 = __ballot(v.y == t);
        unsigned long long m2 = __ballot(v.z == t);
        unsigned long long m3 = __ballot(v.w == t);
        while (m0) { int l = __ffsll(m0) - 1; m0 &= m0 - 1;
            int s = (c0 + l) * 4 + 0;
            float4 r = in4[(size_t)(b * S_ + s) * (H_ / 4) + lane];
            acc.x += r.x; acc.y += r.y; acc.z += r.z; acc.w += r.w; c++; }
        while (m1) { int l = __ffsll(m1) - 1; m1 &= m1 - 1;
            int s = (c0 + l) * 4 + 1;
            float4 r = in4[(size_t)(b * S_ + s) * (H_ / 4) + lane];
            acc.x += r.x; acc.y += r.y; acc.z += r.z; acc.w += r.w; c++; }
        while (m2) { int l = __ffsll(m2) - 1; m2 &= m2 - 1;
            int s = (c0 + l) * 4 + 2;
            float4 r = in4[(size_t)(b * S_ + s) * (H_ / 4) + lane];
            acc.x += r.x; acc.y += r.y; acc.z += r.z; acc.w += r.w; c++; }
        while (m3) { int l = __ffsll(m3) - 1; m3 &= m3 - 1;
            int s = (c0 + l) * 4 + 3;
            float4 r = in4[(size_t)(b * S_ + s) * (H_ / 4) + lane];
            acc.x += r.x; acc.y += r.y; acc.z += r.z; acc.w += r.w; c++; }
    }

    float inv = (c > 0) ? (1.0f / (float)c) : 0.0f;   // empty row -> just emb
    float4 e = reinterpret_cast<const float4*>(seq_emb)[t * (H_ / 4) + lane];
    float4 o;
    o.x = acc.x * inv + e.x;
    o.y = acc.y * inv + e.y;
    o.z = acc.z * inv + e.z;
    o.w = acc.w * inv + e.w;
    reinterpret_cast<float4*>(out)[(size_t)bt * (H_ / 4) + lane] = o;
}

extern "C" void kernel_launch(void* const* d_in, const int* in_sizes, int n_in,
                              void* d_out, int out_size, void* d_ws, size_t ws_size,
                              hipStream_t stream) {
    const float* inputs  = (const float*)d_in[0];   // [B,S,H]
    const float* ttt     = (const float*)d_in[1];   // [B,T,S]
    const float* seq_emb = (const float*)d_in[2];   // [T,H]
    float* out = (float*)d_out;                     // [B,T,H]
    int* L = (int*)d_ws;                            // B*S ints (128 KiB)

    // K1: cost-paired early-exit column-max (256 blocks = 1/CU, 2 strips each)
    colmax_paired_kernel<<<NSTRIPS / 2, 256, 0, stream>>>(ttt, L);

    // K2: fused gather + mean + emb  (B*T/4 blocks, 1 wave per output row)
    gather_mean_kernel<<<B_ * T_ / 4, 256, 0, stream>>>(inputs, L, seq_emb, out);
}

// Round 11
// 30.072 us; speedup vs baseline: 1.6404x; 1.0374x over previous
//
#include <hip/hip_runtime.h>

// Problem constants (match reference setup_inputs)
#define B_ 8
#define T_ 1024
#define S_ 4096
#define H_ 256

#define STRIP 64           // tokens per K1 block
#define CHUNK 128          // tag rows per early-exit check (4 waves x 32 rows)

// K1: top-down early-exit column-max, software-pipelined.
// 512 blocks x 4 waves (2 blocks/CU, 8 waves/CU). Lane owns one token column;
// wave w owns 32 rows of each 128-row chunk (coalesced 256B row loads).
// Chain de-serialization vs R7:
//  - next chunk's 32 loads issue BEFORE processing current (latency overlaps
//    compare+sync; costs <=1 chunk overshoot traffic after exit)
//  - per-wave best kept in registers; exit via found-mask ballot + ONE
//    __syncthreads per chunk (ping-pong LDS slot kills the read/write hazard)
//  - cross-wave max-combine deferred to a single epilogue
__global__ void __launch_bounds__(256) colmax_pipe_kernel(const float* __restrict__ ttt,
                                                          int* __restrict__ L) {
    __shared__ unsigned long long wmask[2][4];
    __shared__ int red[4][STRIP];
    const int strippos = blockIdx.x >> 3;   // low s0 (expensive) first
    const int b  = blockIdx.x & 7;
    const int s0 = strippos * STRIP;
    const int w    = threadIdx.x >> 6;
    const int lane = threadIdx.x & 63;

    const float* colbase = ttt + (size_t)b * T_ * S_ + s0 + lane;

    int best = -1;
    int par = 0;
    float v[32], vn[32];

    // prologue: load top chunk (rows T-CHUNK .. T-1), wave w's 32-row slice
    {
        const float* p = colbase + (size_t)(T_ - CHUNK + w * 32) * S_;
#pragma unroll
        for (int j = 0; j < 32; ++j)
            v[j] = p[(size_t)j * S_];
    }

    for (int thi = T_; thi > 0; thi -= CHUNK) {
        const int t0 = thi - CHUNK + w * 32;
        // prefetch next chunk while current is processed
        if (thi > CHUNK) {
            const float* pn = colbase + (size_t)(t0 - CHUNK) * S_;
#pragma unroll
            for (int j = 0; j < 32; ++j)
                vn[j] = pn[(size_t)j * S_];
        }
        // process current chunk (ascending j -> in-chunk max; chunks visited
        // top-down so "first found" is the global max for this lane)
        int lm = -1;
#pragma unroll
        for (int j = 0; j < 32; ++j)
            if (v[j] > 0.0f) lm = t0 + j;
        best = max(best, lm);

        wmask[par][w] = __ballot(best >= 0);    // all lanes write same value
        __syncthreads();
        unsigned long long all = wmask[par][0] | wmask[par][1]
                               | wmask[par][2] | wmask[par][3];
        if (all == ~0ull) break;                // uniform across block
        par ^= 1;
#pragma unroll
        for (int j = 0; j < 32; ++j)
            v[j] = vn[j];
    }

    // epilogue: one cross-wave max-combine, then write L
    red[w][lane] = best;
    __syncthreads();
    if (threadIdx.x < STRIP) {
        int m = max(max(red[0][threadIdx.x], red[1][threadIdx.x]),
                    max(red[2][threadIdx.x], red[3][threadIdx.x]));
        L[b * S_ + s0 + threadIdx.x] = m;
    }
}

// K2: gather + mean + seq_emb, fused — EXACT R7 form (proven best, absmax 0.0).
// One wave per (b,t) output row; scans L[b,:] with int4 loads (256 tokens per
// iteration via 4 ballots); each matching token contributes a coalesced
// float4-per-lane row of inputs. No atomics.
__global__ void gather_mean_kernel(const float* __restrict__ inputs,
                                   const int* __restrict__ L,
                                   const float* __restrict__ seq_emb,
                                   float* __restrict__ out) {
    int wid  = threadIdx.x >> 6;
    int lane = threadIdx.x & 63;
    int bt = blockIdx.x * 4 + wid;               // (b*T + t), 4 waves per block
    int b = bt >> 10;                            // / T_
    int t = bt & (T_ - 1);

    const int4* Lb4 = reinterpret_cast<const int4*>(L + b * S_);
    const float4* in4 = reinterpret_cast<const float4*>(inputs);

    float4 acc = {0.0f, 0.0f, 0.0f, 0.0f};
    int c = 0;

#pragma unroll 4
    for (int c0 = 0; c0 < S_ / 4; c0 += 64) {    // int4 index space
        int4 v = Lb4[c0 + lane];
        unsigned long long m0 = __ballot(v.x == t);
        unsigned long long m1 = __ballot(v.y == t);
        unsigned long long m2 = __ballot(v.z == t);
        unsigned long long m3 = __ballot(v.w == t);
        while (m0) { int l = __ffsll(m0) - 1; m0 &= m0 - 1;
            int s = (c0 + l) * 4 + 0;
            float4 r = in4[(size_t)(b * S_ + s) * (H_ / 4) + lane];
            acc.x += r.x; acc.y += r.y; acc.z += r.z; acc.w += r.w; c++; }
        while (m1) { int l = __ffsll(m1) - 1; m1 &= m1 - 1;
            int s = (c0 + l) * 4 + 1;
            float4 r = in4[(size_t)(b * S_ + s) * (H_ / 4) + lane];
            acc.x += r.x; acc.y += r.y; acc.z += r.z; acc.w += r.w; c++; }
        while (m2) { int l = __ffsll(m2) - 1; m2 &= m2 - 1;
            int s = (c0 + l) * 4 + 2;
            float4 r = in4[(size_t)(b * S_ + s) * (H_ / 4) + lane];
            acc.x += r.x; acc.y += r.y; acc.z += r.z; acc.w += r.w; c++; }
        while (m3) { int l = __ffsll(m3) - 1; m3 &= m3 - 1;
            int s = (c0 + l) * 4 + 3;
            float4 r = in4[(size_t)(b * S_ + s) * (H_ / 4) + lane];
            acc.x += r.x; acc.y += r.y; acc.z += r.z; acc.w += r.w; c++; }
    }

    float inv = (c > 0) ? (1.0f / (float)c) : 0.0f;   // empty row -> just emb
    float4 e = reinterpret_cast<const float4*>(seq_emb)[t * (H_ / 4) + lane];
    float4 o;
    o.x = acc.x * inv + e.x;
    o.y = acc.y * inv + e.y;
    o.z = acc.z * inv + e.z;
    o.w = acc.w * inv + e.w;
    reinterpret_cast<float4*>(out)[(size_t)bt * (H_ / 4) + lane] = o;
}

extern "C" void kernel_launch(void* const* d_in, const int* in_sizes, int n_in,
                              void* d_out, int out_size, void* d_ws, size_t ws_size,
                              hipStream_t stream) {
    const float* inputs  = (const float*)d_in[0];   // [B,S,H]
    const float* ttt     = (const float*)d_in[1];   // [B,T,S]
    const float* seq_emb = (const float*)d_in[2];   // [T,H]
    float* out = (float*)d_out;                     // [B,T,H]
    int* L = (int*)d_ws;                            // B*S ints (128 KiB)

    // K1: software-pipelined early-exit column-max (512 blocks x 4 waves)
    colmax_pipe_kernel<<<B_ * (S_ / STRIP), 256, 0, stream>>>(ttt, L);

    // K2: fused gather + mean + emb  (B*T/4 blocks, 1 wave per output row)
    gather_mean_kernel<<<B_ * T_ / 4, 256, 0, stream>>>(inputs, L, seq_emb, out);
}

// Round 12
// 28.619 us; speedup vs baseline: 1.7237x; 1.0508x over previous
//
#include <hip/hip_runtime.h>

// Problem constants (match reference setup_inputs)
#define B_ 8
#define T_ 1024
#define S_ 4096
#define H_ 256

#define STRIP 64           // tokens per K1 block
#define CHUNK 128          // tag rows per early-exit check (4 waves x 32 rows)

// K1: top-down early-exit column-max, software-pipelined (R11 form), plus a
// free epilogue: per-strip [Lmin, Lmax] over found tokens (12 shuffles + one
// int2 store). range[] lets K2 skip whole strips.
__global__ void __launch_bounds__(256) colmax_pipe_kernel(const float* __restrict__ ttt,
                                                          int* __restrict__ L,
                                                          int2* __restrict__ range) {
    __shared__ unsigned long long wmask[2][4];
    __shared__ int red[4][STRIP];
    const int strippos = blockIdx.x >> 3;   // low s0 (expensive) first
    const int b  = blockIdx.x & 7;
    const int s0 = strippos * STRIP;
    const int w    = threadIdx.x >> 6;
    const int lane = threadIdx.x & 63;

    const float* colbase = ttt + (size_t)b * T_ * S_ + s0 + lane;

    int best = -1;
    int par = 0;
    float v[32], vn[32];

    // prologue: load top chunk (rows T-CHUNK .. T-1), wave w's 32-row slice
    {
        const float* p = colbase + (size_t)(T_ - CHUNK + w * 32) * S_;
#pragma unroll
        for (int j = 0; j < 32; ++j)
            v[j] = p[(size_t)j * S_];
    }

    for (int thi = T_; thi > 0; thi -= CHUNK) {
        const int t0 = thi - CHUNK + w * 32;
        // prefetch next chunk while current is processed
        if (thi > CHUNK) {
            const float* pn = colbase + (size_t)(t0 - CHUNK) * S_;
#pragma unroll
            for (int j = 0; j < 32; ++j)
                vn[j] = pn[(size_t)j * S_];
        }
        // process current chunk (ascending j -> in-chunk max; chunks visited
        // top-down so first-found is the global max for this lane)
        int lm = -1;
#pragma unroll
        for (int j = 0; j < 32; ++j)
            if (v[j] > 0.0f) lm = t0 + j;
        best = max(best, lm);

        wmask[par][w] = __ballot(best >= 0);    // all lanes write same value
        __syncthreads();
        unsigned long long all = wmask[par][0] | wmask[par][1]
                               | wmask[par][2] | wmask[par][3];
        if (all == ~0ull) break;                // uniform across block
        par ^= 1;
#pragma unroll
        for (int j = 0; j < 32; ++j)
            v[j] = vn[j];
    }

    // epilogue: cross-wave max-combine -> L, plus strip [Lmin,Lmax] -> range
    red[w][lane] = best;
    __syncthreads();
    if (threadIdx.x < STRIP) {                  // exactly wave 0, all 64 lanes
        const int tid = threadIdx.x;
        int m = max(max(red[0][tid], red[1][tid]),
                    max(red[2][tid], red[3][tid]));
        L[b * S_ + s0 + tid] = m;
        int mn = (m < 0) ? 0x7fffffff : m;      // not-found -> +INF for min
        int mx = m;                             // not-found -1 never wins max
#pragma unroll
        for (int k = 32; k >= 1; k >>= 1) {
            mn = min(mn, __shfl_xor(mn, k));
            mx = max(mx, __shfl_xor(mx, k));
        }
        if (tid == 0) {
            int2 rg = {mn, mx};                 // empty strip -> (INT_MAX,-1): no t matches
            range[b * (S_ / STRIP) + strippos] = rg;
        }
    }
}

// K2: range-filtered gather + mean + seq_emb. One wave per (b,t) output row.
// Lane = strip: one ballot over per-strip [Lmin,Lmax] selects candidate strips
// (L[b,s]==t implies t is within strip(s)'s range). Only those strips' 64 L
// values are read (coalesced 256B); matches gather coalesced float4 input
// rows. Ascending strip then ascending bit -> ascending s (absmax-0 order).
__global__ void __launch_bounds__(256) gather_range_kernel(const float* __restrict__ inputs,
                                                           const int* __restrict__ L,
                                                           const int2* __restrict__ range,
                                                           const float* __restrict__ seq_emb,
                                                           float* __restrict__ out) {
    const int wid  = threadIdx.x >> 6;
    const int lane = threadIdx.x & 63;
    const int bt = blockIdx.x * 4 + wid;         // (b*T + t), 4 waves per block
    const int b = bt >> 10;
    const int t = bt & (T_ - 1);

    const float4* in4 = reinterpret_cast<const float4*>(inputs);

    int2 rg = range[b * (S_ / STRIP) + lane];    // lane = strip id (64 strips)
    unsigned long long smask = __ballot(rg.x <= t && t <= rg.y);

    float4 acc = {0.0f, 0.0f, 0.0f, 0.0f};
    int c = 0;

    while (smask) {                              // wave-uniform loop
        int strip = __ffsll(smask) - 1; smask &= smask - 1;
        int Lv = L[b * S_ + strip * STRIP + lane];
        unsigned long long bm = __ballot(Lv == t);
        while (bm) {
            int l = __ffsll(bm) - 1; bm &= bm - 1;
            int s = strip * STRIP + l;
            float4 r = in4[(size_t)(b * S_ + s) * (H_ / 4) + lane];
            acc.x += r.x; acc.y += r.y; acc.z += r.z; acc.w += r.w; c++;
        }
    }

    float inv = (c > 0) ? (1.0f / (float)c) : 0.0f;   // empty row -> just emb
    float4 e = reinterpret_cast<const float4*>(seq_emb)[t * (H_ / 4) + lane];
    float4 o;
    o.x = acc.x * inv + e.x;
    o.y = acc.y * inv + e.y;
    o.z = acc.z * inv + e.z;
    o.w = acc.w * inv + e.w;
    reinterpret_cast<float4*>(out)[(size_t)bt * (H_ / 4) + lane] = o;
}

extern "C" void kernel_launch(void* const* d_in, const int* in_sizes, int n_in,
                              void* d_out, int out_size, void* d_ws, size_t ws_size,
                              hipStream_t stream) {
    const float* inputs  = (const float*)d_in[0];   // [B,S,H]
    const float* ttt     = (const float*)d_in[1];   // [B,T,S]
    const float* seq_emb = (const float*)d_in[2];   // [T,H]
    float* out = (float*)d_out;                     // [B,T,H]

    int* L = (int*)d_ws;                            // B*S ints (128 KiB)
    int2* range = (int2*)(L + B_ * S_);             // 512 int2 (4 KiB)

    // K1: software-pipelined early-exit column-max + strip ranges
    colmax_pipe_kernel<<<B_ * (S_ / STRIP), 256, 0, stream>>>(ttt, L, range);

    // K2: range-filtered gather + mean + emb (B*T/4 blocks, 1 wave per row)
    gather_range_kernel<<<B_ * T_ / 4, 256, 0, stream>>>(inputs, L, range, seq_emb, out);
}